// Round 8
// baseline (141.112 us; speedup 1.0000x reference)
//
#include <hip/hip_runtime.h>

typedef __attribute__((ext_vector_type(4))) float f32x4;
typedef __attribute__((ext_vector_type(8))) short s16x8;
typedef unsigned short u16;

#define DEVI __device__ __forceinline__

// fp32 -> bf16 round-to-nearest-even
DEVI u16 f2bf(float f) {
    union { float f; unsigned int u; } v; v.f = f;
    unsigned int r = v.u + 0x7FFFu + ((v.u >> 16) & 1u);
    return (u16)(r >> 16);
}
DEVI float bf2f(u16 b) {
    union { unsigned int u; float f; } v; v.u = ((unsigned int)b) << 16;
    return v.f;
}

typedef __attribute__((address_space(1))) void gv_t;   // global
typedef __attribute__((address_space(3))) void sv_t;   // LDS

#define GLOAD16(SRC, DST) __builtin_amdgcn_global_load_lds( \
    (gv_t*)(SRC), (sv_t*)(DST), 16, 0, 0)

DEVI f32x4 mfma_bf16(s16x8 a, s16x8 b, f32x4 c) {
    return __builtin_amdgcn_mfma_f32_16x16x32_bf16(a, b, c, 0, 0, 0);
}

// ---------------------------------------------------------------------------
// NT GEMM, split-K, reg-staged with in-register fp32->bf16 conversion.
// C_part[z] = A[M][K] * W[n][K]^T -> bf16 partials (no bias).
// A dtype: fp32 (AF32=true, x) or bf16 (false, attn out). W: always fp32.
// 128x128 tile, BK=64, 512 threads = 8 waves of 64x32, 16x16x32 MFMA.
// Staging: global_load_dwordx4 -> regs -> cvt -> swizzled ds_write_b128.
// Double-buffered LDS (64 KB -> 2 blocks/CU). ONE __syncthreads per K-tile;
// at the barrier there is ZERO outstanding VMEM (loads for t+1 are issued at
// iter top and fully consumed by the cvt+ds_write before the barrier), so
// the barrier's vmcnt(0) drain costs nothing -- the m97-structure stall is
// structurally removed. Load latency hides under frag-read + 16 MFMA.
// XOR chunk swizzle on write AND read (rule both-sides; 0 conflicts proven).
// XCD map: 8 consecutive M-tiles of one N-stripe per XCD (R5-proven).
// ---------------------------------------------------------------------------
template<bool AF32>
__global__ __launch_bounds__(512, 4) void gemmrs(
    const void* __restrict__ Ap, int lda, int kit, int ntot,
    const float* __restrict__ W0, int t0, int n0, int c0,
    const float* __restrict__ W1, int t1, int n1, int c1,
    const float* __restrict__ W2, int t2, int n2, int c2,
    u16* __restrict__ C, int ldc, long long cstride)
{
    __shared__ u16 Als[2][128 * 64];
    __shared__ u16 Bls[2][128 * 64];

    const int lin = blockIdx.x;
    const int xc  = lin & 7;
    const int mm  = lin >> 3;
    const int nbl = xc + 8 * (mm >> 3);
    const int yt  = mm & 7;
    if (nbl >= ntot) return;   // uniform per block; no barriers executed

    const float* Af = (const float*)Ap;
    const u16*   Ab = (const u16*)Ap;

    const int tid  = threadIdx.x;
    const int lane = tid & 63;
    const int wid  = tid >> 6;          // 0..7
    const int li   = lane & 15;
    const int lg   = lane >> 4;
    const int m0   = yt * 128;

    const float* W; int nt0, nsz, cb;
    if (nbl < t0)           { W = W0; nt0 = nbl * 128;             nsz = n0; cb = c0; }
    else if (nbl < t0 + t1) { W = W1; nt0 = (nbl - t0) * 128;      nsz = n1; cb = c1; }
    else                    { W = W2; nt0 = (nbl - t0 - t1) * 128; nsz = n2; cb = c2; }

    const int z  = blockIdx.z;
    const int S  = gridDim.z;
    const int it0 = (z * kit) / S;
    const int it1 = ((z + 1) * kit) / S;
    u16* Cp = C + (long long)z * cstride;

    const int wm = (wid >> 2) * 64;     // {0, 64}
    const int wn = (wid & 3) * 32;      // {0, 32, 64, 96}

    // per-thread staging geometry: 2 rows (j*64 + tid/8), chunk c8 = tid&7.
    const int srow = tid >> 3;          // 0..63
    const int c8   = tid & 7;
    const int sc   = c8 ^ (srow & 7);   // swizzled chunk (same for both j)
    const int wrow0 = (nt0 + srow      > nsz - 1) ? nsz - 1 : nt0 + srow;
    const int wrow1 = (nt0 + srow + 64 > nsz - 1) ? nsz - 1 : nt0 + srow + 64;

    f32x4 acc[4][2];
    #pragma unroll
    for (int mi = 0; mi < 4; ++mi)
        #pragma unroll
        for (int ni = 0; ni < 2; ++ni)
            acc[mi][ni] = (f32x4){0.f, 0.f, 0.f, 0.f};

    // staged registers for one K-tile
    f32x4 ra[2][2];      // A fp32 path
    s16x8 rab[2];        // A bf16 path
    f32x4 rw[2][2];      // W fp32

#define LOADT(TT)                                                               \
    do {                                                                        \
        int k0_ = (TT) * 64;                                                    \
        _Pragma("unroll")                                                       \
        for (int j = 0; j < 2; ++j) {                                           \
            int row_ = j * 64 + srow;                                           \
            if (AF32) {                                                         \
                const float* p_ = Af + (size_t)(m0 + row_) * lda + k0_ + c8 * 8;\
                ra[j][0] = *(const f32x4*)p_;                                   \
                ra[j][1] = *(const f32x4*)(p_ + 4);                             \
            } else {                                                            \
                rab[j] = *(const s16x8*)(Ab + (size_t)(m0 + row_) * lda + k0_ + c8 * 8); \
            }                                                                   \
            int wr_ = j ? wrow1 : wrow0;                                        \
            const float* q_ = W + (size_t)wr_ * lda + k0_ + c8 * 8;             \
            rw[j][0] = *(const f32x4*)q_;                                       \
            rw[j][1] = *(const f32x4*)(q_ + 4);                                 \
        }                                                                       \
    } while (0)

#define WRITET(BI)                                                              \
    do {                                                                        \
        _Pragma("unroll")                                                       \
        for (int j = 0; j < 2; ++j) {                                           \
            int row_ = j * 64 + srow;                                           \
            s16x8 va_;                                                          \
            if (AF32) {                                                         \
                _Pragma("unroll")                                               \
                for (int e = 0; e < 4; ++e) {                                   \
                    va_[e]     = (short)f2bf(ra[j][0][e]);                      \
                    va_[4 + e] = (short)f2bf(ra[j][1][e]);                      \
                }                                                               \
            } else {                                                            \
                va_ = rab[j];                                                   \
            }                                                                   \
            *(s16x8*)&Als[BI][row_ * 64 + sc * 8] = va_;                        \
            s16x8 vw_;                                                          \
            _Pragma("unroll")                                                   \
            for (int e = 0; e < 4; ++e) {                                       \
                vw_[e]     = (short)f2bf(rw[j][0][e]);                          \
                vw_[4 + e] = (short)f2bf(rw[j][1][e]);                          \
            }                                                                   \
            *(s16x8*)&Bls[BI][row_ * 64 + sc * 8] = vw_;                        \
        }                                                                       \
    } while (0)

    // prologue: tile it0 -> buf 0
    LOADT(it0);
    WRITET(0);
    __syncthreads();

    for (int t = it0; t < it1; ++t) {
        const int bi = (t - it0) & 1;

        if (t + 1 < it1) LOADT(t + 1);   // issue early; consumed after MFMA

        // compute tile t from buf[bi]
        s16x8 bfv[2][2];
        #pragma unroll
        for (int ni = 0; ni < 2; ++ni)
            #pragma unroll
            for (int kc = 0; kc < 2; ++kc) {
                int row = wn + ni * 16 + li;
                int ch  = (kc * 4 + lg) ^ (row & 7);
                bfv[ni][kc] = *(const s16x8*)&Bls[bi][row * 64 + ch * 8];
            }
        #pragma unroll
        for (int mi = 0; mi < 4; ++mi) {
            s16x8 af[2];
            #pragma unroll
            for (int kc = 0; kc < 2; ++kc) {
                int row = wm + mi * 16 + li;
                int ch  = (kc * 4 + lg) ^ (row & 7);
                af[kc] = *(const s16x8*)&Als[bi][row * 64 + ch * 8];
            }
            #pragma unroll
            for (int ni = 0; ni < 2; ++ni)
                #pragma unroll
                for (int kc = 0; kc < 2; ++kc)
                    acc[mi][ni] = mfma_bf16(af[kc], bfv[ni][kc], acc[mi][ni]);
        }

        if (t + 1 < it1) WRITET(bi ^ 1); // cvt+ds_write next tile (other buf)

        __syncthreads();   // lgkm drained; NO outstanding VMEM here
    }
#undef LOADT
#undef WRITET

    #pragma unroll
    for (int ni = 0; ni < 2; ++ni) {
        int colr = nt0 + wn + ni * 16 + li;
        if (colr < nsz) {
            #pragma unroll
            for (int mi = 0; mi < 4; ++mi)
                #pragma unroll
                for (int r = 0; r < 4; ++r) {
                    int row = m0 + wm + mi * 16 + lg * 4 + r;
                    Cp[(size_t)row * ldc + cb + colr] = f2bf(acc[mi][ni][r]);
                }
        }
    }
}

// ---------------------------------------------------------------------------
// RoPE + bias + bf16 convert from 3 bf16 split-K partials.
// ---------------------------------------------------------------------------
__global__ void rope_kernel(const u16* __restrict__ qkvp,
                            const float* __restrict__ qb, const float* __restrict__ kb,
                            const float* __restrict__ vb,
                            u16* __restrict__ qo, u16* __restrict__ ko, u16* __restrict__ vo)
{
    const long long PST = 1024LL * 5120;
    int id = blockIdx.x * 256 + threadIdx.x;   // 1024 * 2560
    int s  = id / 2560;
    int r  = id % 2560;
    const u16* r0 = qkvp + (size_t)s * 5120;
    if (r < 2304) {
        bool isq = r < 2048;
        int rr   = isq ? r : r - 2048;
        int hh   = rr >> 5;
        int d    = rr & 31;
        int col  = (isq ? 0 : 4096) + hh * 64 + d;
        int bcol = isq ? col : col - 4096;
        const float* bias = isq ? qb : kb;
        float t1 = bf2f(r0[col])      + bf2f(r0[col + PST])      + bf2f(r0[col + 2 * PST])      + bias[bcol];
        float t2 = bf2f(r0[col + 32]) + bf2f(r0[col + 32 + PST]) + bf2f(r0[col + 32 + 2 * PST]) + bias[bcol + 32];
        // inv_freq = 150000^(-d/32) = exp2(-d * log2(150000)/32)
        float ang = (float)s * exp2f((float)d * -0.5373314f);
        float sn, cs;
        sincosf(ang, &sn, &cs);
        float sc = isq ? 0.125f : 1.0f;    // fold score scale HD^-0.5 into q
        float o1 = (t1 * cs - t2 * sn) * sc;
        float o2 = (t1 * sn + t2 * cs) * sc;
        u16* dst = isq ? qo : ko;
        int ldd  = isq ? 4096 : 512;
        dst[(size_t)s * ldd + bcol]      = f2bf(o1);
        dst[(size_t)s * ldd + bcol + 32] = f2bf(o2);
    } else {
        int e = (r - 2304) * 2;
        int c0 = 4608 + e;
        float v0 = bf2f(r0[c0])     + bf2f(r0[c0 + PST])     + bf2f(r0[c0 + 2 * PST])     + vb[e];
        float v1 = bf2f(r0[c0 + 1]) + bf2f(r0[c0 + 1 + PST]) + bf2f(r0[c0 + 1 + 2 * PST]) + vb[e + 1];
        vo[(size_t)s * 512 + e]     = f2bf(v0);
        vo[(size_t)s * 512 + e + 1] = f2bf(v1);
    }
}

// ---------------------------------------------------------------------------
// out = sum of 5 bf16 split-K partials + bias (fp32)
// ---------------------------------------------------------------------------
__global__ void reduce_out_kernel(const u16* __restrict__ parts,
                                  const float* __restrict__ bias,
                                  float* __restrict__ out)
{
    int id = blockIdx.x * 256 + threadIdx.x;      // 0..368639 (8-elem groups)
    const long long stride = 1024LL * 2880;
    long long base = (long long)id * 8;
    float s[8];
    #pragma unroll
    for (int j = 0; j < 8; ++j) s[j] = 0.f;
    #pragma unroll
    for (int p = 0; p < 5; ++p) {
        s16x8 v = *(const s16x8*)(parts + p * stride + base);
        #pragma unroll
        for (int j = 0; j < 8; ++j) s[j] += bf2f((u16)v[j]);
    }
    int cb = (int)(base % 2880);
    f32x4 b0 = *(const f32x4*)(bias + cb);
    f32x4 b1 = *(const f32x4*)(bias + cb + 4);
    f32x4 o0 = {s[0] + b0[0], s[1] + b0[1], s[2] + b0[2], s[3] + b0[3]};
    f32x4 o1 = {s[4] + b1[0], s[5] + b1[1], s[6] + b1[2], s[7] + b1[3]};
    *(f32x4*)(out + base)     = o0;
    *(f32x4*)(out + base + 4) = o1;
}

// ---------------------------------------------------------------------------
// Sliding-window GQA attention with sinks (unchanged, proven).
// ---------------------------------------------------------------------------
__global__ __launch_bounds__(256, 2) void attn_kernel(
    const u16* __restrict__ Q, const u16* __restrict__ Kb, const u16* __restrict__ Vb,
    const float* __restrict__ sinks, u16* __restrict__ Ob)
{
    __shared__ u16 Kls[64 * 64];
    __shared__ u16 Pls[4][16 * 72];

    const int h    = blockIdx.x;
    const int qblk = blockIdx.y;
    const int kvh  = h >> 3;
    const int tid  = threadIdx.x;
    const int lane = tid & 63;
    const int w    = tid >> 6;
    const int li   = lane & 15;
    const int lg   = lane >> 4;
    const int qw   = qblk * 64 + w * 16;

    s16x8 aq[2];
    {
        const u16* qrow = Q + ((size_t)(qw + li) * 64 + h) * 64 + lg * 8;
        aq[0] = *(const s16x8*)(qrow);
        aq[1] = *(const s16x8*)(qrow + 32);
    }

    const float snk = sinks[h];
    float m_run[4], l_run[4];
    f32x4 oacc[4];
    #pragma unroll
    for (int r = 0; r < 4; ++r) { m_run[r] = snk; l_run[r] = 1.0f; }
    #pragma unroll
    for (int ni = 0; ni < 4; ++ni) oacc[ni] = (f32x4){0.f, 0.f, 0.f, 0.f};

    const int srow = tid >> 3;
    const int slc  = (tid & 7) ^ (srow & 7);

    for (int t = 0; t < 3; ++t) {
        int jt = qblk - 2 + t;
        if (jt < 0) continue;
        int j0 = jt * 64;

        #pragma unroll
        for (int it = 0; it < 2; ++it) {
            const u16* src = Kb + ((size_t)(j0 + it * 32 + srow) * 8 + kvh) * 64 + slc * 8;
            GLOAD16(src, &Kls[(it * 256 + w * 64) * 8]);
        }
        __syncthreads();

        f32x4 sc[4];
        #pragma unroll
        for (int nf = 0; nf < 4; ++nf) {
            sc[nf] = (f32x4){0.f, 0.f, 0.f, 0.f};
            #pragma unroll
            for (int kc = 0; kc < 2; ++kc) {
                int row = nf * 16 + li;
                int ch  = (kc * 4 + lg) ^ (row & 7);
                s16x8 bk = *(const s16x8*)&Kls[row * 64 + ch * 8];
                sc[nf] = mfma_bf16(aq[kc], bk, sc[nf]);
            }
        }

        #pragma unroll
        for (int r = 0; r < 4; ++r) {
            const int qg = qw + lg * 4 + r;
            float mx = -1e30f;
            #pragma unroll
            for (int nf = 0; nf < 4; ++nf) {
                int jg = j0 + nf * 16 + li;
                bool ok = (jg <= qg) && (qg - jg < 128);
                float v = ok ? sc[nf][r] : -1e30f;
                sc[nf][r] = v;
                mx = fmaxf(mx, v);
            }
            #pragma unroll
            for (int off = 1; off < 16; off <<= 1)
                mx = fmaxf(mx, __shfl_xor(mx, off));
            float mnew = fmaxf(m_run[r], mx);
            float corr = __expf(m_run[r] - mnew);
            m_run[r] = mnew;
            float rs = 0.f;
            #pragma unroll
            for (int nf = 0; nf < 4; ++nf) {
                float p = __expf(sc[nf][r] - mnew);
                rs += p;
                Pls[w][(lg * 4 + r) * 72 + nf * 16 + li] = f2bf(p);
            }
            #pragma unroll
            for (int off = 1; off < 16; off <<= 1)
                rs += __shfl_xor(rs, off);
            l_run[r] = l_run[r] * corr + rs;
            #pragma unroll
            for (int ni = 0; ni < 4; ++ni) oacc[ni][r] *= corr;
        }
        __syncthreads();   // all K reads done; P writes drained

        #pragma unroll
        for (int kc = 0; kc < 2; ++kc) {
            s16x8 pa = *(const s16x8*)&Pls[w][li * 72 + kc * 32 + lg * 8];
            #pragma unroll
            for (int ni = 0; ni < 4; ++ni) {
                const u16* vsrc = Vb + ((size_t)(j0 + kc * 32 + lg * 8) * 8 + kvh) * 64 + ni * 16 + li;
                s16x8 bv;
                #pragma unroll
                for (int i = 0; i < 8; ++i) bv[i] = (short)vsrc[(size_t)i * 512];
                oacc[ni] = mfma_bf16(pa, bv, oacc[ni]);
            }
        }
    }

    #pragma unroll
    for (int r = 0; r < 4; ++r) {
        float inv = 1.0f / l_run[r];
        #pragma unroll
        for (int ni = 0; ni < 4; ++ni)
            Ob[((size_t)(qw + lg * 4 + r) * 64 + h) * 64 + ni * 16 + li] = f2bf(oacc[ni][r] * inv);
    }
}

// ---------------------------------------------------------------------------
extern "C" void kernel_launch(void* const* d_in, const int* in_sizes, int n_in,
                              void* d_out, int out_size, void* d_ws, size_t ws_size,
                              hipStream_t stream)
{
    const float* x     = (const float*)d_in[0];
    const float* wq_w  = (const float*)d_in[1];
    const float* wq_b  = (const float*)d_in[2];
    const float* wk_w  = (const float*)d_in[3];
    const float* wk_b  = (const float*)d_in[4];
    const float* wv_w  = (const float*)d_in[5];
    const float* wv_b  = (const float*)d_in[6];
    const float* wo_w  = (const float*)d_in[7];
    const float* wo_b  = (const float*)d_in[8];
    const float* sinks = (const float*)d_in[9];

    char* ws = (char*)d_ws;
    // Layout (no cvt pass any more -- GEMMs read fp32 inputs directly):
    //   [0, 10,485,760)           qr | kr | vbf           (rope -> attn)
    //   [10,485,760, 18,874,368)  attb                    (attn -> gemm2)
    //   [35,389,440, 66,846,720)  qkvp 3 bf16 partials    (gemm1 -> rope)
    //   [58,982,400, 88,473,600)  oprt 5 bf16 partials    (gemm2 -> reduce)
    //       (overlaps dead qkvp tail -- qkvp dead after rope)
    u16*   qkvp = (u16*)(ws + 35389440ULL);      // 3 bf16 partials, stride 1024*5120
    u16*   qr   = (u16*)(ws + 0);
    u16*   kr   = (u16*)(ws + 8388608ULL);
    u16*   vbf  = (u16*)(ws + 9437184ULL);
    u16*   attb = (u16*)(ws + 10485760ULL);
    u16*   oprt = (u16*)(ws + 58982400ULL);      // 5 bf16 partials, stride 1024*2880

    (void)in_sizes; (void)n_in; (void)out_size; (void)ws_size;

    // 1) fused QKV projection (reads x, wq, wk, wv fp32 directly),
    //    split-K=3 -> 3 bf16 partials [1024][5120]
    gemmrs<true><<<dim3(320, 1, 3), 512, 0, stream>>>(x, 2880, 45, 40,
        wq_w, 32, 4096, 0,
        wk_w, 4, 512, 4096,
        wv_w, 4, 512, 4608,
        qkvp, 5120, 1024LL * 5120);
    // 2) RoPE + partial-sum + bias + convert (q pre-scaled by 0.125)
    rope_kernel<<<10240, 256, 0, stream>>>(qkvp, wq_b, wk_b, wv_b, qr, kr, vbf);
    // 3) attention -> attb bf16 [1024][4096]
    attn_kernel<<<dim3(64, 16), 256, 0, stream>>>(qr, kr, vbf, sinks, attb);
    // 4) output projection (A = attb bf16, W = wo fp32),
    //    split-K=5 -> 5 bf16 partials [1024][2880]
    gemmrs<false><<<dim3(192, 1, 5), 512, 0, stream>>>(attb, 4096, 64, 23,
        wo_w, 23, 2880, 0,
        wo_w, 0, 0, 0,
        wo_w, 0, 0, 0,
        oprt, 2880, 1024LL * 2880);
    // 5) reduce partials + bias -> d_out fp32 [1024][2880]
    reduce_out_kernel<<<1440, 256, 0, stream>>>(oprt, wo_b, (float*)d_out);
}

// Round 9
// 139.369 us; speedup vs baseline: 1.0125x; 1.0125x over previous
//
#include <hip/hip_runtime.h>

typedef __attribute__((ext_vector_type(4))) float f32x4;
typedef __attribute__((ext_vector_type(8))) short s16x8;
typedef unsigned short u16;

#define DEVI __device__ __forceinline__

// fp32 -> bf16 round-to-nearest-even
DEVI u16 f2bf(float f) {
    union { float f; unsigned int u; } v; v.f = f;
    unsigned int r = v.u + 0x7FFFu + ((v.u >> 16) & 1u);
    return (u16)(r >> 16);
}
DEVI float bf2f(u16 b) {
    union { unsigned int u; float f; } v; v.u = ((unsigned int)b) << 16;
    return v.f;
}

typedef __attribute__((address_space(1))) void gv_t;   // global
typedef __attribute__((address_space(3))) void sv_t;   // LDS

#define GLOAD16(SRC, DST) __builtin_amdgcn_global_load_lds( \
    (gv_t*)(SRC), (sv_t*)(DST), 16, 0, 0)

DEVI f32x4 mfma_bf16(s16x8 a, s16x8 b, f32x4 c) {
    return __builtin_amdgcn_mfma_f32_16x16x32_bf16(a, b, c, 0, 0, 0);
}

// ---------------------------------------------------------------------------
// fp32 -> bf16: x only (5.9 MB out; ~3 us). Weights stay fp32 -- the GEMM
// converts them in-register (saves the 38 us full-cvt pass, R8 measurement).
// ---------------------------------------------------------------------------
__global__ void cvt_x_kernel(const float* __restrict__ x, u16* __restrict__ xb)
{
    int id = blockIdx.x * 256 + threadIdx.x;   // 0 .. 737279 (f32x4 units)
    f32x4 v = *(const f32x4*)(x + (size_t)id * 4);
    union { u16 u[4]; unsigned long long ll; } o;
    #pragma unroll
    for (int j = 0; j < 4; ++j) o.u[j] = f2bf(v[j]);
    *(unsigned long long*)(xb + (size_t)id * 4) = o.ll;
}

// ---------------------------------------------------------------------------
// NT GEMM, split-K, HYBRID staging (R5 loop + fp32-W reg-stage):
//   A (bf16): global_load_lds width 16, linear LDS dest, inverse-swz source.
//   W (fp32): 4x global_load_dwordx4 -> regs (16 VGPR) -> f2bf -> 2 swizzled
//             ds_write_b128. W loads issued FIRST each iter so the compiler's
//             dependency wait (vmcnt(2)) leaves the 2 A-gloads in flight.
// C_part[z] = A[M][K](bf16) * W[n][K](fp32)^T -> bf16 partials (no bias).
// 128x128 tile, BK=64, 512 threads = 8 waves of 64x32, 16x16x32 MFMA.
// Double-buffered LDS (64 KB -> 2 blocks/CU -> 16 waves/CU). One
// __syncthreads per K-tile (safety: drains A-gloads + lgkm; W-cvt+write
// happen before it, under the MFMA shadow).
// XOR chunk swizzle write+read (0 conflicts, proven R1-R8). XCD map: 8
// consecutive M-tiles of one N-stripe per XCD (R5-proven).
// ---------------------------------------------------------------------------
__global__ __launch_bounds__(512, 4) void gemmhy(
    const u16* __restrict__ A, int lda, int kit, int ntot,
    const float* __restrict__ W0, int t0, int n0, int c0,
    const float* __restrict__ W1, int t1, int n1, int c1,
    const float* __restrict__ W2, int t2, int n2, int c2,
    u16* __restrict__ C, int ldc, long long cstride)
{
    __shared__ u16 Als[2][128 * 64];
    __shared__ u16 Bls[2][128 * 64];

    const int lin = blockIdx.x;
    const int xc  = lin & 7;
    const int mm  = lin >> 3;
    const int nbl = xc + 8 * (mm >> 3);
    const int yt  = mm & 7;
    if (nbl >= ntot) return;   // uniform per block; no barriers executed

    const int tid  = threadIdx.x;
    const int lane = tid & 63;
    const int wid  = tid >> 6;          // 0..7
    const int li   = lane & 15;
    const int lg   = lane >> 4;
    const int m0   = yt * 128;

    const float* W; int nt0, nsz, cb;
    if (nbl < t0)           { W = W0; nt0 = nbl * 128;             nsz = n0; cb = c0; }
    else if (nbl < t0 + t1) { W = W1; nt0 = (nbl - t0) * 128;      nsz = n1; cb = c1; }
    else                    { W = W2; nt0 = (nbl - t0 - t1) * 128; nsz = n2; cb = c2; }

    const int z  = blockIdx.z;
    const int S  = gridDim.z;
    const int it0 = (z * kit) / S;
    const int it1 = ((z + 1) * kit) / S;
    u16* Cp = C + (long long)z * cstride;

    const int wm = (wid >> 2) * 64;     // {0, 64}
    const int wn = (wid & 3) * 32;      // {0, 32, 64, 96}

    f32x4 acc[4][2];
    #pragma unroll
    for (int mi = 0; mi < 4; ++mi)
        #pragma unroll
        for (int ni = 0; ni < 2; ++ni)
            acc[mi][ni] = (f32x4){0.f, 0.f, 0.f, 0.f};

    // --- A staging geometry (gload_lds): 2 chunk loads per thread ---
    //     chunk g = j*512 + tid; row = g>>3; c8 = g&7; src chunk = c8^(row&7)
    // --- W staging geometry (reg): thread owns 16 consecutive floats of one
    //     row: row_ = tid>>2 (0..127), c80 = (tid&3)*2 chunks (of 8 floats)
    const int wrowl = tid >> 2;
    const int c80   = (tid & 3) * 2;
    const int wrowg = (nt0 + wrowl > nsz - 1) ? nsz - 1 : nt0 + wrowl;

    f32x4 rw[4];   // 16 floats of W, one K-tile

#define LOADW(TT)                                                               \
    do {                                                                        \
        const float* q_ = W + (size_t)wrowg * lda + (TT) * 64 + c80 * 8;        \
        rw[0] = *(const f32x4*)q_;                                              \
        rw[1] = *(const f32x4*)(q_ + 4);                                        \
        rw[2] = *(const f32x4*)(q_ + 8);                                        \
        rw[3] = *(const f32x4*)(q_ + 12);                                       \
    } while (0)

#define GLOADA(TT, BI)                                                          \
    do {                                                                        \
        int k0_ = (TT) * 64;                                                    \
        _Pragma("unroll")                                                       \
        for (int j = 0; j < 2; ++j) {                                           \
            int g_   = j * 512 + tid;                                           \
            int row_ = g_ >> 3;                                                 \
            int cs_  = (g_ & 7) ^ (row_ & 7);                                   \
            GLOAD16(A + (size_t)(m0 + row_) * lda + k0_ + cs_ * 8,              \
                    &Als[BI][g_ * 8]);                                          \
        }                                                                       \
    } while (0)

#define WRITEW(BI)                                                              \
    do {                                                                        \
        s16x8 w0_, w1_;                                                         \
        _Pragma("unroll")                                                       \
        for (int e = 0; e < 4; ++e) {                                           \
            w0_[e]     = (short)f2bf(rw[0][e]);                                 \
            w0_[4 + e] = (short)f2bf(rw[1][e]);                                 \
            w1_[e]     = (short)f2bf(rw[2][e]);                                 \
            w1_[4 + e] = (short)f2bf(rw[3][e]);                                 \
        }                                                                       \
        int s0_ = c80 ^ (wrowl & 7);                                            \
        int s1_ = (c80 + 1) ^ (wrowl & 7);                                      \
        *(s16x8*)&Bls[BI][wrowl * 64 + s0_ * 8] = w0_;                          \
        *(s16x8*)&Bls[BI][wrowl * 64 + s1_ * 8] = w1_;                          \
    } while (0)

    // prologue: tile it0 -> buf 0
    LOADW(it0);
    GLOADA(it0, 0);
    WRITEW(0);           // compiler inserts vmcnt wait for rw (A-glds stay out)
    __syncthreads();     // drains A-glds + lgkm

    for (int t = it0; t < it1; ++t) {
        const int bi = (t - it0) & 1;

        if (t + 1 < it1) {
            LOADW(t + 1);          // issue W loads first (oldest in queue)
            GLOADA(t + 1, bi ^ 1); // then A direct-to-LDS (other buffer)
        }

        // compute tile t from buf[bi]
        s16x8 bfv[2][2];
        #pragma unroll
        for (int ni = 0; ni < 2; ++ni)
            #pragma unroll
            for (int kc = 0; kc < 2; ++kc) {
                int row = wn + ni * 16 + li;
                int ch  = (kc * 4 + lg) ^ (row & 7);
                bfv[ni][kc] = *(const s16x8*)&Bls[bi][row * 64 + ch * 8];
            }
        #pragma unroll
        for (int mi = 0; mi < 4; ++mi) {
            s16x8 af[2];
            #pragma unroll
            for (int kc = 0; kc < 2; ++kc) {
                int row = wm + mi * 16 + li;
                int ch  = (kc * 4 + lg) ^ (row & 7);
                af[kc] = *(const s16x8*)&Als[bi][row * 64 + ch * 8];
            }
            #pragma unroll
            for (int ni = 0; ni < 2; ++ni)
                #pragma unroll
                for (int kc = 0; kc < 2; ++kc)
                    acc[mi][ni] = mfma_bf16(af[kc], bfv[ni][kc], acc[mi][ni]);
        }

        if (t + 1 < it1) WRITEW(bi ^ 1);  // cvt+write W under MFMA shadow

        __syncthreads();   // safety: drains remaining VMEM (A-glds) + lgkm
    }
#undef LOADW
#undef GLOADA
#undef WRITEW

    #pragma unroll
    for (int ni = 0; ni < 2; ++ni) {
        int colr = nt0 + wn + ni * 16 + li;
        if (colr < nsz) {
            #pragma unroll
            for (int mi = 0; mi < 4; ++mi)
                #pragma unroll
                for (int r = 0; r < 4; ++r) {
                    int row = m0 + wm + mi * 16 + lg * 4 + r;
                    Cp[(size_t)row * ldc + cb + colr] = f2bf(acc[mi][ni][r]);
                }
        }
    }
}

// ---------------------------------------------------------------------------
// RoPE + bias + bf16 convert from 3 bf16 split-K partials. VECTORIZED:
// each thread handles 8 consecutive dims (bf16x8 loads, 16B stores).
// Groups per row: 256 q (64 heads x 4 d-groups) + 32 k + 64 v = 352.
// ---------------------------------------------------------------------------
__global__ void rope_kernel(const u16* __restrict__ qkvp,
                            const float* __restrict__ qb, const float* __restrict__ kb,
                            const float* __restrict__ vb,
                            u16* __restrict__ qo, u16* __restrict__ ko, u16* __restrict__ vo)
{
    const long long PST = 1024LL * 5120;
    int id = blockIdx.x * 256 + threadIdx.x;   // 1024 * 352
    int s  = id / 352;
    int g  = id % 352;
    const u16* r0 = qkvp + (size_t)s * 5120;

    if (g < 288) {                      // q (g<256) or k
        bool isq = g < 256;
        int gg   = isq ? g : g - 256;
        int hh   = gg >> 2;
        int dg   = gg & 3;
        int col0 = (isq ? 0 : 4096) + hh * 64 + dg * 8;
        int bcol = isq ? col0 : col0 - 4096;
        const float* bias = isq ? qb : kb;

        float t1[8], t2[8];
        #pragma unroll
        for (int e = 0; e < 8; ++e) { t1[e] = bias[bcol + e]; t2[e] = bias[bcol + 32 + e]; }
        #pragma unroll
        for (int p = 0; p < 3; ++p) {
            s16x8 lo = *(const s16x8*)(r0 + col0 + p * PST);
            s16x8 hi = *(const s16x8*)(r0 + col0 + 32 + p * PST);
            #pragma unroll
            for (int e = 0; e < 8; ++e) {
                t1[e] += bf2f((u16)lo[e]);
                t2[e] += bf2f((u16)hi[e]);
            }
        }
        float sc = isq ? 0.125f : 1.0f;    // fold HD^-0.5 into q
        s16x8 o1, o2;
        #pragma unroll
        for (int e = 0; e < 8; ++e) {
            int d = dg * 8 + e;
            float ang = (float)s * exp2f((float)d * -0.5373314f);
            float sn, cs;
            sincosf(ang, &sn, &cs);
            o1[e] = (short)f2bf((t1[e] * cs - t2[e] * sn) * sc);
            o2[e] = (short)f2bf((t1[e] * sn + t2[e] * cs) * sc);
        }
        u16* dst = isq ? qo : ko;
        int ldd  = isq ? 4096 : 512;
        *(s16x8*)(dst + (size_t)s * ldd + bcol)      = o1;
        *(s16x8*)(dst + (size_t)s * ldd + bcol + 32) = o2;
    } else {                            // v: plain sum + bias
        int gg   = g - 288;             // 0..63
        int col0 = 4608 + gg * 8;
        float t[8];
        #pragma unroll
        for (int e = 0; e < 8; ++e) t[e] = vb[gg * 8 + e];
        #pragma unroll
        for (int p = 0; p < 3; ++p) {
            s16x8 v = *(const s16x8*)(r0 + col0 + p * PST);
            #pragma unroll
            for (int e = 0; e < 8; ++e) t[e] += bf2f((u16)v[e]);
        }
        s16x8 o;
        #pragma unroll
        for (int e = 0; e < 8; ++e) o[e] = (short)f2bf(t[e]);
        *(s16x8*)(vo + (size_t)s * 512 + gg * 8) = o;
    }
}

// ---------------------------------------------------------------------------
// out = sum of 5 bf16 split-K partials + bias (fp32)
// ---------------------------------------------------------------------------
__global__ void reduce_out_kernel(const u16* __restrict__ parts,
                                  const float* __restrict__ bias,
                                  float* __restrict__ out)
{
    int id = blockIdx.x * 256 + threadIdx.x;      // 0..368639 (8-elem groups)
    const long long stride = 1024LL * 2880;
    long long base = (long long)id * 8;
    float s[8];
    #pragma unroll
    for (int j = 0; j < 8; ++j) s[j] = 0.f;
    #pragma unroll
    for (int p = 0; p < 5; ++p) {
        s16x8 v = *(const s16x8*)(parts + p * stride + base);
        #pragma unroll
        for (int j = 0; j < 8; ++j) s[j] += bf2f((u16)v[j]);
    }
    int cb = (int)(base % 2880);
    f32x4 b0 = *(const f32x4*)(bias + cb);
    f32x4 b1 = *(const f32x4*)(bias + cb + 4);
    f32x4 o0 = {s[0] + b0[0], s[1] + b0[1], s[2] + b0[2], s[3] + b0[3]};
    f32x4 o1 = {s[4] + b1[0], s[5] + b1[1], s[6] + b1[2], s[7] + b1[3]};
    *(f32x4*)(out + base)     = o0;
    *(f32x4*)(out + base + 4) = o1;
}

// ---------------------------------------------------------------------------
// Sliding-window GQA attention with sinks (unchanged, proven).
// ---------------------------------------------------------------------------
__global__ __launch_bounds__(256, 2) void attn_kernel(
    const u16* __restrict__ Q, const u16* __restrict__ Kb, const u16* __restrict__ Vb,
    const float* __restrict__ sinks, u16* __restrict__ Ob)
{
    __shared__ u16 Kls[64 * 64];
    __shared__ u16 Pls[4][16 * 72];

    const int h    = blockIdx.x;
    const int qblk = blockIdx.y;
    const int kvh  = h >> 3;
    const int tid  = threadIdx.x;
    const int lane = tid & 63;
    const int w    = tid >> 6;
    const int li   = lane & 15;
    const int lg   = lane >> 4;
    const int qw   = qblk * 64 + w * 16;

    s16x8 aq[2];
    {
        const u16* qrow = Q + ((size_t)(qw + li) * 64 + h) * 64 + lg * 8;
        aq[0] = *(const s16x8*)(qrow);
        aq[1] = *(const s16x8*)(qrow + 32);
    }

    const float snk = sinks[h];
    float m_run[4], l_run[4];
    f32x4 oacc[4];
    #pragma unroll
    for (int r = 0; r < 4; ++r) { m_run[r] = snk; l_run[r] = 1.0f; }
    #pragma unroll
    for (int ni = 0; ni < 4; ++ni) oacc[ni] = (f32x4){0.f, 0.f, 0.f, 0.f};

    const int srow = tid >> 3;
    const int slc  = (tid & 7) ^ (srow & 7);

    for (int t = 0; t < 3; ++t) {
        int jt = qblk - 2 + t;
        if (jt < 0) continue;
        int j0 = jt * 64;

        #pragma unroll
        for (int it = 0; it < 2; ++it) {
            const u16* src = Kb + ((size_t)(j0 + it * 32 + srow) * 8 + kvh) * 64 + slc * 8;
            GLOAD16(src, &Kls[(it * 256 + w * 64) * 8]);
        }
        __syncthreads();

        f32x4 sc[4];
        #pragma unroll
        for (int nf = 0; nf < 4; ++nf) {
            sc[nf] = (f32x4){0.f, 0.f, 0.f, 0.f};
            #pragma unroll
            for (int kc = 0; kc < 2; ++kc) {
                int row = nf * 16 + li;
                int ch  = (kc * 4 + lg) ^ (row & 7);
                s16x8 bk = *(const s16x8*)&Kls[row * 64 + ch * 8];
                sc[nf] = mfma_bf16(aq[kc], bk, sc[nf]);
            }
        }

        #pragma unroll
        for (int r = 0; r < 4; ++r) {
            const int qg = qw + lg * 4 + r;
            float mx = -1e30f;
            #pragma unroll
            for (int nf = 0; nf < 4; ++nf) {
                int jg = j0 + nf * 16 + li;
                bool ok = (jg <= qg) && (qg - jg < 128);
                float v = ok ? sc[nf][r] : -1e30f;
                sc[nf][r] = v;
                mx = fmaxf(mx, v);
            }
            #pragma unroll
            for (int off = 1; off < 16; off <<= 1)
                mx = fmaxf(mx, __shfl_xor(mx, off));
            float mnew = fmaxf(m_run[r], mx);
            float corr = __expf(m_run[r] - mnew);
            m_run[r] = mnew;
            float rs = 0.f;
            #pragma unroll
            for (int nf = 0; nf < 4; ++nf) {
                float p = __expf(sc[nf][r] - mnew);
                rs += p;
                Pls[w][(lg * 4 + r) * 72 + nf * 16 + li] = f2bf(p);
            }
            #pragma unroll
            for (int off = 1; off < 16; off <<= 1)
                rs += __shfl_xor(rs, off);
            l_run[r] = l_run[r] * corr + rs;
            #pragma unroll
            for (int ni = 0; ni < 4; ++ni) oacc[ni][r] *= corr;
        }
        __syncthreads();   // all K reads done; P writes drained

        #pragma unroll
        for (int kc = 0; kc < 2; ++kc) {
            s16x8 pa = *(const s16x8*)&Pls[w][li * 72 + kc * 32 + lg * 8];
            #pragma unroll
            for (int ni = 0; ni < 4; ++ni) {
                const u16* vsrc = Vb + ((size_t)(j0 + kc * 32 + lg * 8) * 8 + kvh) * 64 + ni * 16 + li;
                s16x8 bv;
                #pragma unroll
                for (int i = 0; i < 8; ++i) bv[i] = (short)vsrc[(size_t)i * 512];
                oacc[ni] = mfma_bf16(pa, bv, oacc[ni]);
            }
        }
    }

    #pragma unroll
    for (int r = 0; r < 4; ++r) {
        float inv = 1.0f / l_run[r];
        #pragma unroll
        for (int ni = 0; ni < 4; ++ni)
            Ob[((size_t)(qw + lg * 4 + r) * 64 + h) * 64 + ni * 16 + li] = f2bf(oacc[ni][r] * inv);
    }
}

// ---------------------------------------------------------------------------
extern "C" void kernel_launch(void* const* d_in, const int* in_sizes, int n_in,
                              void* d_out, int out_size, void* d_ws, size_t ws_size,
                              hipStream_t stream)
{
    const float* x     = (const float*)d_in[0];
    const float* wq_w  = (const float*)d_in[1];
    const float* wq_b  = (const float*)d_in[2];
    const float* wk_w  = (const float*)d_in[3];
    const float* wk_b  = (const float*)d_in[4];
    const float* wv_w  = (const float*)d_in[5];
    const float* wv_b  = (const float*)d_in[6];
    const float* wo_w  = (const float*)d_in[7];
    const float* wo_b  = (const float*)d_in[8];
    const float* sinks = (const float*)d_in[9];

    char* ws = (char*)d_ws;
    // Layout (peak ~88.5 MB):
    //   [0, 5,898,240)            xb                      (cvt_x -> gemm1)
    //       after rope overlays:  qr@0|kr|vbf|attb        (rope -> gemm2)
    //   [35,389,440, 66,846,720)  qkvp 3 bf16 partials    (gemm1 -> rope)
    //   [58,982,400, 88,473,600)  oprt 5 bf16 partials    (gemm2 -> reduce)
    //       (overlaps dead qkvp tail -- qkvp dead after rope)
    u16*   xb   = (u16*)(ws + 0);
    u16*   qkvp = (u16*)(ws + 35389440ULL);      // 3 bf16 partials, stride 1024*5120
    u16*   qr   = (u16*)(ws + 0);
    u16*   kr   = (u16*)(ws + 8388608ULL);
    u16*   vbf  = (u16*)(ws + 9437184ULL);
    u16*   attb = (u16*)(ws + 10485760ULL);
    u16*   oprt = (u16*)(ws + 58982400ULL);      // 5 bf16 partials, stride 1024*2880

    (void)in_sizes; (void)n_in; (void)out_size; (void)ws_size;

    // 1) x -> bf16 (weights stay fp32; GEMMs convert in-register)
    cvt_x_kernel<<<2880, 256, 0, stream>>>(x, xb);
    // 2) fused QKV projection, split-K=3 -> 3 bf16 partials [1024][5120]
    gemmhy<<<dim3(320, 1, 3), 512, 0, stream>>>(xb, 2880, 45, 40,
        wq_w, 32, 4096, 0,
        wk_w, 4, 512, 4096,
        wv_w, 4, 512, 4608,
        qkvp, 5120, 1024LL * 5120);
    // 3) RoPE + partial-sum + bias + convert (q pre-scaled by 0.125)
    rope_kernel<<<1408, 256, 0, stream>>>(qkvp, wq_b, wk_b, wv_b, qr, kr, vbf);
    // 4) attention -> attb bf16 [1024][4096]
    attn_kernel<<<dim3(64, 16), 256, 0, stream>>>(qr, kr, vbf, sinks, attb);
    // 5) output projection (A = attb bf16, W = wo fp32),
    //    split-K=5 -> 5 bf16 partials [1024][2880]
    gemmhy<<<dim3(192, 1, 5), 512, 0, stream>>>(attb, 4096, 64, 23,
        wo_w, 23, 2880, 0,
        wo_w, 0, 0, 0,
        wo_w, 0, 0, 0,
        oprt, 2880, 1024LL * 2880);
    // 6) reduce partials + bias -> d_out fp32 [1024][2880]
    reduce_out_kernel<<<1440, 256, 0, stream>>>(oprt, wo_b, (float*)d_out);
}

// Round 10
// 130.918 us; speedup vs baseline: 1.0779x; 1.0646x over previous
//
#include <hip/hip_runtime.h>

typedef __attribute__((ext_vector_type(4))) float f32x4;
typedef __attribute__((ext_vector_type(8))) short s16x8;
typedef unsigned short u16;

#define DEVI __device__ __forceinline__

// fp32 -> bf16 round-to-nearest-even
DEVI u16 f2bf(float f) {
    union { float f; unsigned int u; } v; v.f = f;
    unsigned int r = v.u + 0x7FFFu + ((v.u >> 16) & 1u);
    return (u16)(r >> 16);
}
DEVI float bf2f(u16 b) {
    union { unsigned int u; float f; } v; v.u = ((unsigned int)b) << 16;
    return v.f;
}

typedef __attribute__((address_space(1))) void gv_t;   // global
typedef __attribute__((address_space(3))) void sv_t;   // LDS

#define GLOAD16(SRC, DST) __builtin_amdgcn_global_load_lds( \
    (gv_t*)(SRC), (sv_t*)(DST), 16, 0, 0)

DEVI f32x4 mfma_bf16(s16x8 a, s16x8 b, f32x4 c) {
    return __builtin_amdgcn_mfma_f32_16x16x32_bf16(a, b, c, 0, 0, 0);
}

// ---------------------------------------------------------------------------
// fp32 -> bf16 conversion of x, wq, wk, wv, wo (one fused streaming pass)
// ---------------------------------------------------------------------------
__global__ void cvt_all_kernel(
    const float* __restrict__ x,  const float* __restrict__ wq, const float* __restrict__ wk,
    const float* __restrict__ wv, const float* __restrict__ wo,
    u16* __restrict__ xb, u16* __restrict__ wqb, u16* __restrict__ wkb,
    u16* __restrict__ wvb, u16* __restrict__ wob)
{
    int id = blockIdx.x * 256 + threadIdx.x;   // 0 .. 7372800-1 (f32x4 units)
    const float* s; u16* d; int off;
    if      (id < 737280)  { s = x;  d = xb;  off = id; }
    else if (id < 3686400) { s = wq; d = wqb; off = id - 737280; }
    else if (id < 4055040) { s = wk; d = wkb; off = id - 3686400; }
    else if (id < 4423680) { s = wv; d = wvb; off = id - 4055040; }
    else                   { s = wo; d = wob; off = id - 4423680; }
    f32x4 v = *(const f32x4*)(s + (size_t)off * 4);
    union { u16 u[4]; unsigned long long ll; } o;
    #pragma unroll
    for (int j = 0; j < 4; ++j) o.u[j] = f2bf(v[j]);
    *(unsigned long long*)(d + (size_t)off * 4) = o.ll;
}

// ---------------------------------------------------------------------------
// NT GEMM, split-K, m97-EXACT structure (the 874-TF-certified config):
// 256 threads, 4 waves of 64x64, 128x128 tile, BK=64, SINGLE 32 KB LDS
// buffer, plain 2-barrier K-loop (stage -> sync -> frags+MFMA -> sync).
// Pipelining is implicit cross-block wave overlap at 4 blocks/CU.
// __launch_bounds__(256,3): VGPR cap ~170 >> ~115 needed -> NO SPILL
// (R3's failure was (256,5) -> VGPR 48 -> 82 MB scratch; this fixes that).
// C_part[z] = A[M][K](bf16) * W[n][K](bf16)^T -> bf16 partials (no bias).
// XOR chunk swizzle source+read (0 conflicts proven). XCD map: 8
// consecutive M-tiles of one N-stripe per XCD.
// ---------------------------------------------------------------------------
__global__ __launch_bounds__(256, 3) void gemm_m97(
    const u16* __restrict__ A, int lda, int kit, int ntot,
    const u16* __restrict__ W0, int t0, int n0, int c0,
    const u16* __restrict__ W1, int t1, int n1, int c1,
    const u16* __restrict__ W2, int t2, int n2, int c2,
    u16* __restrict__ C, int ldc, long long cstride)
{
    __shared__ u16 Als[128 * 64];
    __shared__ u16 Bls[128 * 64];

    const int lin = blockIdx.x;
    const int xc  = lin & 7;
    const int mm  = lin >> 3;
    const int nbl = xc + 8 * (mm >> 3);
    const int yt  = mm & 7;
    if (nbl >= ntot) return;   // uniform per block; no barriers executed

    const int tid  = threadIdx.x;
    const int lane = tid & 63;
    const int wid  = tid >> 6;          // 0..3
    const int li   = lane & 15;
    const int lg   = lane >> 4;
    const int m0   = yt * 128;

    const u16* W; int nt0, nsz, cb;
    if (nbl < t0)           { W = W0; nt0 = nbl * 128;             nsz = n0; cb = c0; }
    else if (nbl < t0 + t1) { W = W1; nt0 = (nbl - t0) * 128;      nsz = n1; cb = c1; }
    else                    { W = W2; nt0 = (nbl - t0 - t1) * 128; nsz = n2; cb = c2; }

    const int z  = blockIdx.z;
    const int S  = gridDim.z;
    const int it0 = (z * kit) / S;
    const int it1 = ((z + 1) * kit) / S;
    u16* Cp = C + (long long)z * cstride;

    const int wm = (wid >> 1) * 64;
    const int wn = (wid & 1) * 64;

    f32x4 acc[4][4];
    #pragma unroll
    for (int mi = 0; mi < 4; ++mi)
        #pragma unroll
        for (int ni = 0; ni < 4; ++ni)
            acc[mi][ni] = (f32x4){0.f, 0.f, 0.f, 0.f};

    // staging: 4 A + 4 B chunk-loads per thread (chunk g = s*256 + tid)
    const int srow = tid >> 3;                 // 0..31 (row within 32-row slab)
    const int slc  = (tid & 7) ^ (srow & 7);   // inverse-swizzled source chunk

    for (int it = it0; it < it1; ++it) {
        const int k0 = it * 64;
        #pragma unroll
        for (int s_ = 0; s_ < 4; ++s_) {
            const u16* sa = A + (size_t)(m0 + s_ * 32 + srow) * lda + k0 + slc * 8;
            GLOAD16(sa, &Als[(s_ * 256 + tid) * 8]);
        }
        #pragma unroll
        for (int s_ = 0; s_ < 4; ++s_) {
            int wr = nt0 + s_ * 32 + srow;
            if (wr > nsz - 1) wr = nsz - 1;    // ragged-N clamp (stores guarded)
            const u16* sb = W + (size_t)wr * lda + k0 + slc * 8;
            GLOAD16(sb, &Bls[(s_ * 256 + tid) * 8]);
        }
        __syncthreads();

        s16x8 af[4][2], bfv[4][2];
        #pragma unroll
        for (int mi = 0; mi < 4; ++mi)
            #pragma unroll
            for (int kc = 0; kc < 2; ++kc) {
                int row = wm + mi * 16 + li;
                int ch  = (kc * 4 + lg) ^ (row & 7);
                af[mi][kc] = *(const s16x8*)&Als[row * 64 + ch * 8];
            }
        #pragma unroll
        for (int ni = 0; ni < 4; ++ni)
            #pragma unroll
            for (int kc = 0; kc < 2; ++kc) {
                int row = wn + ni * 16 + li;
                int ch  = (kc * 4 + lg) ^ (row & 7);
                bfv[ni][kc] = *(const s16x8*)&Bls[row * 64 + ch * 8];
            }
        #pragma unroll
        for (int mi = 0; mi < 4; ++mi)
            #pragma unroll
            for (int ni = 0; ni < 4; ++ni)
                #pragma unroll
                for (int kc = 0; kc < 2; ++kc)
                    acc[mi][ni] = mfma_bf16(af[mi][kc], bfv[ni][kc], acc[mi][ni]);
        __syncthreads();
    }

    #pragma unroll
    for (int ni = 0; ni < 4; ++ni) {
        int colr = nt0 + wn + ni * 16 + li;
        if (colr < nsz) {
            #pragma unroll
            for (int mi = 0; mi < 4; ++mi)
                #pragma unroll
                for (int r = 0; r < 4; ++r) {
                    int row = m0 + wm + mi * 16 + lg * 4 + r;
                    Cp[(size_t)row * ldc + cb + colr] = f2bf(acc[mi][ni][r]);
                }
        }
    }
}

// ---------------------------------------------------------------------------
// RoPE + bias + bf16 convert from 3 bf16 split-K partials. Vectorized:
// each thread handles 8 consecutive dims (bf16x8 loads, 16B stores).
// Groups per row: 256 q (64 heads x 4 d-groups) + 32 k + 64 v = 352.
// ---------------------------------------------------------------------------
__global__ void rope_kernel(const u16* __restrict__ qkvp,
                            const float* __restrict__ qb, const float* __restrict__ kb,
                            const float* __restrict__ vb,
                            u16* __restrict__ qo, u16* __restrict__ ko, u16* __restrict__ vo)
{
    const long long PST = 1024LL * 5120;
    int id = blockIdx.x * 256 + threadIdx.x;   // 1024 * 352
    int s  = id / 352;
    int g  = id % 352;
    const u16* r0 = qkvp + (size_t)s * 5120;

    if (g < 288) {                      // q (g<256) or k
        bool isq = g < 256;
        int gg   = isq ? g : g - 256;
        int hh   = gg >> 2;
        int dg   = gg & 3;
        int col0 = (isq ? 0 : 4096) + hh * 64 + dg * 8;
        int bcol = isq ? col0 : col0 - 4096;
        const float* bias = isq ? qb : kb;

        float t1[8], t2[8];
        #pragma unroll
        for (int e = 0; e < 8; ++e) { t1[e] = bias[bcol + e]; t2[e] = bias[bcol + 32 + e]; }
        #pragma unroll
        for (int p = 0; p < 3; ++p) {
            s16x8 lo = *(const s16x8*)(r0 + col0 + p * PST);
            s16x8 hi = *(const s16x8*)(r0 + col0 + 32 + p * PST);
            #pragma unroll
            for (int e = 0; e < 8; ++e) {
                t1[e] += bf2f((u16)lo[e]);
                t2[e] += bf2f((u16)hi[e]);
            }
        }
        float sc = isq ? 0.125f : 1.0f;    // fold HD^-0.5 into q
        s16x8 o1, o2;
        #pragma unroll
        for (int e = 0; e < 8; ++e) {
            int d = dg * 8 + e;
            float ang = (float)s * exp2f((float)d * -0.5373314f);
            float sn, cs;
            sincosf(ang, &sn, &cs);
            o1[e] = (short)f2bf((t1[e] * cs - t2[e] * sn) * sc);
            o2[e] = (short)f2bf((t1[e] * sn + t2[e] * cs) * sc);
        }
        u16* dst = isq ? qo : ko;
        int ldd  = isq ? 4096 : 512;
        *(s16x8*)(dst + (size_t)s * ldd + bcol)      = o1;
        *(s16x8*)(dst + (size_t)s * ldd + bcol + 32) = o2;
    } else {                            // v: plain sum + bias
        int gg   = g - 288;             // 0..63
        int col0 = 4608 + gg * 8;
        float t[8];
        #pragma unroll
        for (int e = 0; e < 8; ++e) t[e] = vb[gg * 8 + e];
        #pragma unroll
        for (int p = 0; p < 3; ++p) {
            s16x8 v = *(const s16x8*)(r0 + col0 + p * PST);
            #pragma unroll
            for (int e = 0; e < 8; ++e) t[e] += bf2f((u16)v[e]);
        }
        s16x8 o;
        #pragma unroll
        for (int e = 0; e < 8; ++e) o[e] = (short)f2bf(t[e]);
        *(s16x8*)(vo + (size_t)s * 512 + gg * 8) = o;
    }
}

// ---------------------------------------------------------------------------
// out = sum of 5 bf16 split-K partials + bias (fp32)
// ---------------------------------------------------------------------------
__global__ void reduce_out_kernel(const u16* __restrict__ parts,
                                  const float* __restrict__ bias,
                                  float* __restrict__ out)
{
    int id = blockIdx.x * 256 + threadIdx.x;      // 0..368639 (8-elem groups)
    const long long stride = 1024LL * 2880;
    long long base = (long long)id * 8;
    float s[8];
    #pragma unroll
    for (int j = 0; j < 8; ++j) s[j] = 0.f;
    #pragma unroll
    for (int p = 0; p < 5; ++p) {
        s16x8 v = *(const s16x8*)(parts + p * stride + base);
        #pragma unroll
        for (int j = 0; j < 8; ++j) s[j] += bf2f((u16)v[j]);
    }
    int cb = (int)(base % 2880);
    f32x4 b0 = *(const f32x4*)(bias + cb);
    f32x4 b1 = *(const f32x4*)(bias + cb + 4);
    f32x4 o0 = {s[0] + b0[0], s[1] + b0[1], s[2] + b0[2], s[3] + b0[3]};
    f32x4 o1 = {s[4] + b1[0], s[5] + b1[1], s[6] + b1[2], s[7] + b1[3]};
    *(f32x4*)(out + base)     = o0;
    *(f32x4*)(out + base + 4) = o1;
}

// ---------------------------------------------------------------------------
// Sliding-window GQA attention with sinks (unchanged, proven).
// ---------------------------------------------------------------------------
__global__ __launch_bounds__(256, 2) void attn_kernel(
    const u16* __restrict__ Q, const u16* __restrict__ Kb, const u16* __restrict__ Vb,
    const float* __restrict__ sinks, u16* __restrict__ Ob)
{
    __shared__ u16 Kls[64 * 64];
    __shared__ u16 Pls[4][16 * 72];

    const int h    = blockIdx.x;
    const int qblk = blockIdx.y;
    const int kvh  = h >> 3;
    const int tid  = threadIdx.x;
    const int lane = tid & 63;
    const int w    = tid >> 6;
    const int li   = lane & 15;
    const int lg   = lane >> 4;
    const int qw   = qblk * 64 + w * 16;

    s16x8 aq[2];
    {
        const u16* qrow = Q + ((size_t)(qw + li) * 64 + h) * 64 + lg * 8;
        aq[0] = *(const s16x8*)(qrow);
        aq[1] = *(const s16x8*)(qrow + 32);
    }

    const float snk = sinks[h];
    float m_run[4], l_run[4];
    f32x4 oacc[4];
    #pragma unroll
    for (int r = 0; r < 4; ++r) { m_run[r] = snk; l_run[r] = 1.0f; }
    #pragma unroll
    for (int ni = 0; ni < 4; ++ni) oacc[ni] = (f32x4){0.f, 0.f, 0.f, 0.f};

    const int srow = tid >> 3;
    const int slc  = (tid & 7) ^ (srow & 7);

    for (int t = 0; t < 3; ++t) {
        int jt = qblk - 2 + t;
        if (jt < 0) continue;
        int j0 = jt * 64;

        #pragma unroll
        for (int it = 0; it < 2; ++it) {
            const u16* src = Kb + ((size_t)(j0 + it * 32 + srow) * 8 + kvh) * 64 + slc * 8;
            GLOAD16(src, &Kls[(it * 256 + w * 64) * 8]);
        }
        __syncthreads();

        f32x4 sc[4];
        #pragma unroll
        for (int nf = 0; nf < 4; ++nf) {
            sc[nf] = (f32x4){0.f, 0.f, 0.f, 0.f};
            #pragma unroll
            for (int kc = 0; kc < 2; ++kc) {
                int row = nf * 16 + li;
                int ch  = (kc * 4 + lg) ^ (row & 7);
                s16x8 bk = *(const s16x8*)&Kls[row * 64 + ch * 8];
                sc[nf] = mfma_bf16(aq[kc], bk, sc[nf]);
            }
        }

        #pragma unroll
        for (int r = 0; r < 4; ++r) {
            const int qg = qw + lg * 4 + r;
            float mx = -1e30f;
            #pragma unroll
            for (int nf = 0; nf < 4; ++nf) {
                int jg = j0 + nf * 16 + li;
                bool ok = (jg <= qg) && (qg - jg < 128);
                float v = ok ? sc[nf][r] : -1e30f;
                sc[nf][r] = v;
                mx = fmaxf(mx, v);
            }
            #pragma unroll
            for (int off = 1; off < 16; off <<= 1)
                mx = fmaxf(mx, __shfl_xor(mx, off));
            float mnew = fmaxf(m_run[r], mx);
            float corr = __expf(m_run[r] - mnew);
            m_run[r] = mnew;
            float rs = 0.f;
            #pragma unroll
            for (int nf = 0; nf < 4; ++nf) {
                float p = __expf(sc[nf][r] - mnew);
                rs += p;
                Pls[w][(lg * 4 + r) * 72 + nf * 16 + li] = f2bf(p);
            }
            #pragma unroll
            for (int off = 1; off < 16; off <<= 1)
                rs += __shfl_xor(rs, off);
            l_run[r] = l_run[r] * corr + rs;
            #pragma unroll
            for (int ni = 0; ni < 4; ++ni) oacc[ni][r] *= corr;
        }
        __syncthreads();   // all K reads done; P writes drained

        #pragma unroll
        for (int kc = 0; kc < 2; ++kc) {
            s16x8 pa = *(const s16x8*)&Pls[w][li * 72 + kc * 32 + lg * 8];
            #pragma unroll
            for (int ni = 0; ni < 4; ++ni) {
                const u16* vsrc = Vb + ((size_t)(j0 + kc * 32 + lg * 8) * 8 + kvh) * 64 + ni * 16 + li;
                s16x8 bv;
                #pragma unroll
                for (int i = 0; i < 8; ++i) bv[i] = (short)vsrc[(size_t)i * 512];
                oacc[ni] = mfma_bf16(pa, bv, oacc[ni]);
            }
        }
    }

    #pragma unroll
    for (int r = 0; r < 4; ++r) {
        float inv = 1.0f / l_run[r];
        #pragma unroll
        for (int ni = 0; ni < 4; ++ni)
            Ob[((size_t)(qw + lg * 4 + r) * 64 + h) * 64 + ni * 16 + li] = f2bf(oacc[ni][r] * inv);
    }
}

// ---------------------------------------------------------------------------
extern "C" void kernel_launch(void* const* d_in, const int* in_sizes, int n_in,
                              void* d_out, int out_size, void* d_ws, size_t ws_size,
                              hipStream_t stream)
{
    const float* x     = (const float*)d_in[0];
    const float* wq_w  = (const float*)d_in[1];
    const float* wq_b  = (const float*)d_in[2];
    const float* wk_w  = (const float*)d_in[3];
    const float* wk_b  = (const float*)d_in[4];
    const float* wv_w  = (const float*)d_in[5];
    const float* wv_b  = (const float*)d_in[6];
    const float* wo_w  = (const float*)d_in[7];
    const float* wo_b  = (const float*)d_in[8];
    const float* sinks = (const float*)d_in[9];

    char* ws = (char*)d_ws;
    // Layout (peak 112.1 MB; 117.9 proven available):
    //   [0, 35,389,440)           xb|wqb|wkb|wvb        (cvt -> gemm1)
    //       after rope overlays:  qr@0|kr|vbf|attb      (rope -> gemm2)
    //   [35,389,440, 66,846,720)  qkvp 3 bf16 partials  (gemm1 -> rope)
    //   [58,982,400, 88,473,600)  oprt 5 bf16 partials  (gemm2 -> reduce)
    //       (overlaps dead qkvp tail -- qkvp dead after rope)
    //   [88,473,600, 112,066,560) wob                   (cvt -> gemm2)
    u16*   xb   = (u16*)(ws + 0);
    u16*   wqb  = (u16*)(ws + 5898240ULL);
    u16*   wkb  = (u16*)(ws + 29491200ULL);
    u16*   wvb  = (u16*)(ws + 32440320ULL);
    u16*   qkvp = (u16*)(ws + 35389440ULL);      // 3 bf16 partials, stride 1024*5120
    u16*   qr   = (u16*)(ws + 0);
    u16*   kr   = (u16*)(ws + 8388608ULL);
    u16*   vbf  = (u16*)(ws + 9437184ULL);
    u16*   attb = (u16*)(ws + 10485760ULL);
    u16*   oprt = (u16*)(ws + 58982400ULL);      // 5 bf16 partials, stride 1024*2880
    u16*   wob  = (u16*)(ws + 88473600ULL);

    (void)in_sizes; (void)n_in; (void)out_size; (void)ws_size;

    // 1) bf16 conversions (x, wq, wk, wv, wo -- one pass)
    cvt_all_kernel<<<28800, 256, 0, stream>>>(x, wq_w, wk_w, wv_w, wo_w,
                                              xb, wqb, wkb, wvb, wob);
    // 2) fused QKV projection, split-K=3 -> 3 bf16 partials [1024][5120]
    //    960 blocks -> ~4 blocks/CU co-resident (m97-level residency, no spill)
    gemm_m97<<<dim3(320, 1, 3), 256, 0, stream>>>(xb, 2880, 45, 40,
        wqb, 32, 4096, 0,
        wkb, 4, 512, 4096,
        wvb, 4, 512, 4608,
        qkvp, 5120, 1024LL * 5120);
    // 3) RoPE + partial-sum + bias + convert (q pre-scaled by 0.125)
    rope_kernel<<<1408, 256, 0, stream>>>(qkvp, wq_b, wk_b, wv_b, qr, kr, vbf);
    // 4) attention -> attb bf16 [1024][4096]
    attn_kernel<<<dim3(64, 16), 256, 0, stream>>>(qr, kr, vbf, sinks, attb);
    // 5) output projection, split-K=5 -> 5 bf16 partials [1024][2880]
    gemm_m97<<<dim3(192, 1, 5), 256, 0, stream>>>(attb, 4096, 64, 23,
        wob, 23, 2880, 0,
        wob, 0, 0, 0,
        wob, 0, 0, 0,
        oprt, 2880, 1024LL * 2880);
    // 6) reduce partials + bias -> d_out fp32 [1024][2880]
    reduce_out_kernel<<<1440, 256, 0, stream>>>(oprt, wo_b, (float*)d_out);
}

// Round 11
// 130.292 us; speedup vs baseline: 1.0830x; 1.0048x over previous
//
#include <hip/hip_runtime.h>

typedef __attribute__((ext_vector_type(4))) float f32x4;
typedef __attribute__((ext_vector_type(8))) short s16x8;
typedef unsigned short u16;

#define DEVI __device__ __forceinline__

// fp32 -> bf16 round-to-nearest-even
DEVI u16 f2bf(float f) {
    union { float f; unsigned int u; } v; v.f = f;
    unsigned int r = v.u + 0x7FFFu + ((v.u >> 16) & 1u);
    return (u16)(r >> 16);
}
DEVI float bf2f(u16 b) {
    union { unsigned int u; float f; } v; v.u = ((unsigned int)b) << 16;
    return v.f;
}

typedef __attribute__((address_space(1))) void gv_t;   // global
typedef __attribute__((address_space(3))) void sv_t;   // LDS

#define GLOAD16(SRC, DST) __builtin_amdgcn_global_load_lds( \
    (gv_t*)(SRC), (sv_t*)(DST), 16, 0, 0)

DEVI f32x4 mfma_bf16(s16x8 a, s16x8 b, f32x4 c) {
    return __builtin_amdgcn_mfma_f32_16x16x32_bf16(a, b, c, 0, 0, 0);
}

// ---------------------------------------------------------------------------
// fp32 -> bf16: x, wq, wk, wv only (123 MB traffic). wo is converted inside
// the GEMM1 launch (extra blocks ride in its idle HBM bandwidth -- GEMM1
// runs at 25% HBM util, R10 measurement).
// ---------------------------------------------------------------------------
__global__ void cvt1_kernel(
    const float* __restrict__ x,  const float* __restrict__ wq, const float* __restrict__ wk,
    const float* __restrict__ wv,
    u16* __restrict__ xb, u16* __restrict__ wqb, u16* __restrict__ wkb,
    u16* __restrict__ wvb)
{
    int id = blockIdx.x * 256 + threadIdx.x;   // 0 .. 4423680-1 (f32x4 units)
    const float* s; u16* d; int off;
    if      (id < 737280)  { s = x;  d = xb;  off = id; }
    else if (id < 3686400) { s = wq; d = wqb; off = id - 737280; }
    else if (id < 4055040) { s = wk; d = wkb; off = id - 3686400; }
    else                   { s = wv; d = wvb; off = id - 4055040; }
    f32x4 v = *(const f32x4*)(s + (size_t)off * 4);
    union { u16 u[4]; unsigned long long ll; } o;
    #pragma unroll
    for (int j = 0; j < 4; ++j) o.u[j] = f2bf(v[j]);
    *(unsigned long long*)(d + (size_t)off * 4) = o.ll;
}

// ---------------------------------------------------------------------------
// NT GEMM, split-K, m97-EXACT structure (R10: best measured, no spill).
// 256 threads, 4 waves of 64x64, 128x128 tile, BK=64, single 32 KB LDS buf,
// plain 2-barrier K-loop; pipelining = implicit cross-block wave overlap.
// NEW (R11): blocks with lin >= gemmx are STREAMING-CVT blocks -- on z==0
// they convert a slice of wo fp32->bf16 (filling GEMM1's idle HBM BW);
// other z exit immediately. GEMM blocks 0..gemmx-1 are bit-identical to R10.
// ---------------------------------------------------------------------------
__global__ __launch_bounds__(256, 3) void gemm_m97(
    const u16* __restrict__ A, int lda, int kit, int ntot, int gemmx,
    const u16* __restrict__ W0, int t0, int n0, int c0,
    const u16* __restrict__ W1, int t1, int n1, int c1,
    const u16* __restrict__ W2, int t2, int n2, int c2,
    u16* __restrict__ C, int ldc, long long cstride,
    const float* __restrict__ cvsrc, u16* __restrict__ cvdst, int cvblk)
{
    __shared__ u16 Als[128 * 64];
    __shared__ u16 Bls[128 * 64];

    const int lin = blockIdx.x;
    const int z   = blockIdx.z;

    if (lin >= gemmx) {                 // streaming-cvt block (wo fp32->bf16)
        if (z == 0 && cvblk > 0) {
            const int cb_  = lin - gemmx;           // 0..cvblk-1
            const int step = cvblk * 256;           // f32x4 stride
            int idx = cb_ * 256 + threadIdx.x;
            #pragma unroll 4
            for (int i = 0; i < 16; ++i) {
                f32x4 v = *(const f32x4*)(cvsrc + (size_t)idx * 4);
                union { u16 u[4]; unsigned long long ll; } o;
                #pragma unroll
                for (int j = 0; j < 4; ++j) o.u[j] = f2bf(v[j]);
                *(unsigned long long*)(cvdst + (size_t)idx * 4) = o.ll;
                idx += step;
            }
        }
        return;
    }

    const int xc  = lin & 7;
    const int mm  = lin >> 3;
    const int nbl = xc + 8 * (mm >> 3);
    const int yt  = mm & 7;
    if (nbl >= ntot) return;   // uniform per block; no barriers executed

    const int tid  = threadIdx.x;
    const int lane = tid & 63;
    const int wid  = tid >> 6;          // 0..3
    const int li   = lane & 15;
    const int lg   = lane >> 4;
    const int m0   = yt * 128;

    const u16* W; int nt0, nsz, cb;
    if (nbl < t0)           { W = W0; nt0 = nbl * 128;             nsz = n0; cb = c0; }
    else if (nbl < t0 + t1) { W = W1; nt0 = (nbl - t0) * 128;      nsz = n1; cb = c1; }
    else                    { W = W2; nt0 = (nbl - t0 - t1) * 128; nsz = n2; cb = c2; }

    const int S  = gridDim.z;
    const int it0 = (z * kit) / S;
    const int it1 = ((z + 1) * kit) / S;
    u16* Cp = C + (long long)z * cstride;

    const int wm = (wid >> 1) * 64;
    const int wn = (wid & 1) * 64;

    f32x4 acc[4][4];
    #pragma unroll
    for (int mi = 0; mi < 4; ++mi)
        #pragma unroll
        for (int ni = 0; ni < 4; ++ni)
            acc[mi][ni] = (f32x4){0.f, 0.f, 0.f, 0.f};

    const int srow = tid >> 3;                 // 0..31 (row within 32-row slab)
    const int slc  = (tid & 7) ^ (srow & 7);   // inverse-swizzled source chunk

    for (int it = it0; it < it1; ++it) {
        const int k0 = it * 64;
        #pragma unroll
        for (int s_ = 0; s_ < 4; ++s_) {
            const u16* sa = A + (size_t)(m0 + s_ * 32 + srow) * lda + k0 + slc * 8;
            GLOAD16(sa, &Als[(s_ * 256 + tid) * 8]);
        }
        #pragma unroll
        for (int s_ = 0; s_ < 4; ++s_) {
            int wr = nt0 + s_ * 32 + srow;
            if (wr > nsz - 1) wr = nsz - 1;    // ragged-N clamp (stores guarded)
            const u16* sb = W + (size_t)wr * lda + k0 + slc * 8;
            GLOAD16(sb, &Bls[(s_ * 256 + tid) * 8]);
        }
        __syncthreads();

        s16x8 af[4][2], bfv[4][2];
        #pragma unroll
        for (int mi = 0; mi < 4; ++mi)
            #pragma unroll
            for (int kc = 0; kc < 2; ++kc) {
                int row = wm + mi * 16 + li;
                int ch  = (kc * 4 + lg) ^ (row & 7);
                af[mi][kc] = *(const s16x8*)&Als[row * 64 + ch * 8];
            }
        #pragma unroll
        for (int ni = 0; ni < 4; ++ni)
            #pragma unroll
            for (int kc = 0; kc < 2; ++kc) {
                int row = wn + ni * 16 + li;
                int ch  = (kc * 4 + lg) ^ (row & 7);
                bfv[ni][kc] = *(const s16x8*)&Bls[row * 64 + ch * 8];
            }
        #pragma unroll
        for (int mi = 0; mi < 4; ++mi)
            #pragma unroll
            for (int ni = 0; ni < 4; ++ni)
                #pragma unroll
                for (int kc = 0; kc < 2; ++kc)
                    acc[mi][ni] = mfma_bf16(af[mi][kc], bfv[ni][kc], acc[mi][ni]);
        __syncthreads();
    }

    #pragma unroll
    for (int ni = 0; ni < 4; ++ni) {
        int colr = nt0 + wn + ni * 16 + li;
        if (colr < nsz) {
            #pragma unroll
            for (int mi = 0; mi < 4; ++mi)
                #pragma unroll
                for (int r = 0; r < 4; ++r) {
                    int row = m0 + wm + mi * 16 + lg * 4 + r;
                    Cp[(size_t)row * ldc + cb + colr] = f2bf(acc[mi][ni][r]);
                }
        }
    }
}

// ---------------------------------------------------------------------------
// RoPE + bias + bf16 convert from 3 bf16 split-K partials. Vectorized:
// each thread handles 8 consecutive dims (bf16x8 loads, 16B stores).
// Groups per row: 256 q (64 heads x 4 d-groups) + 32 k + 64 v = 352.
// ---------------------------------------------------------------------------
__global__ void rope_kernel(const u16* __restrict__ qkvp,
                            const float* __restrict__ qb, const float* __restrict__ kb,
                            const float* __restrict__ vb,
                            u16* __restrict__ qo, u16* __restrict__ ko, u16* __restrict__ vo)
{
    const long long PST = 1024LL * 5120;
    int id = blockIdx.x * 256 + threadIdx.x;   // 1024 * 352
    int s  = id / 352;
    int g  = id % 352;
    const u16* r0 = qkvp + (size_t)s * 5120;

    if (g < 288) {                      // q (g<256) or k
        bool isq = g < 256;
        int gg   = isq ? g : g - 256;
        int hh   = gg >> 2;
        int dg   = gg & 3;
        int col0 = (isq ? 0 : 4096) + hh * 64 + dg * 8;
        int bcol = isq ? col0 : col0 - 4096;
        const float* bias = isq ? qb : kb;

        float t1[8], t2[8];
        #pragma unroll
        for (int e = 0; e < 8; ++e) { t1[e] = bias[bcol + e]; t2[e] = bias[bcol + 32 + e]; }
        #pragma unroll
        for (int p = 0; p < 3; ++p) {
            s16x8 lo = *(const s16x8*)(r0 + col0 + p * PST);
            s16x8 hi = *(const s16x8*)(r0 + col0 + 32 + p * PST);
            #pragma unroll
            for (int e = 0; e < 8; ++e) {
                t1[e] += bf2f((u16)lo[e]);
                t2[e] += bf2f((u16)hi[e]);
            }
        }
        float sc = isq ? 0.125f : 1.0f;    // fold HD^-0.5 into q
        s16x8 o1, o2;
        #pragma unroll
        for (int e = 0; e < 8; ++e) {
            int d = dg * 8 + e;
            float ang = (float)s * exp2f((float)d * -0.5373314f);
            float sn, cs;
            sincosf(ang, &sn, &cs);
            o1[e] = (short)f2bf((t1[e] * cs - t2[e] * sn) * sc);
            o2[e] = (short)f2bf((t1[e] * sn + t2[e] * cs) * sc);
        }
        u16* dst = isq ? qo : ko;
        int ldd  = isq ? 4096 : 512;
        *(s16x8*)(dst + (size_t)s * ldd + bcol)      = o1;
        *(s16x8*)(dst + (size_t)s * ldd + bcol + 32) = o2;
    } else {                            // v: plain sum + bias
        int gg   = g - 288;             // 0..63
        int col0 = 4608 + gg * 8;
        float t[8];
        #pragma unroll
        for (int e = 0; e < 8; ++e) t[e] = vb[gg * 8 + e];
        #pragma unroll
        for (int p = 0; p < 3; ++p) {
            s16x8 v = *(const s16x8*)(r0 + col0 + p * PST);
            #pragma unroll
            for (int e = 0; e < 8; ++e) t[e] += bf2f((u16)v[e]);
        }
        s16x8 o;
        #pragma unroll
        for (int e = 0; e < 8; ++e) o[e] = (short)f2bf(t[e]);
        *(s16x8*)(vo + (size_t)s * 512 + gg * 8) = o;
    }
}

// ---------------------------------------------------------------------------
// out = sum of 5 bf16 split-K partials + bias (fp32)
// ---------------------------------------------------------------------------
__global__ void reduce_out_kernel(const u16* __restrict__ parts,
                                  const float* __restrict__ bias,
                                  float* __restrict__ out)
{
    int id = blockIdx.x * 256 + threadIdx.x;      // 0..368639 (8-elem groups)
    const long long stride = 1024LL * 2880;
    long long base = (long long)id * 8;
    float s[8];
    #pragma unroll
    for (int j = 0; j < 8; ++j) s[j] = 0.f;
    #pragma unroll
    for (int p = 0; p < 5; ++p) {
        s16x8 v = *(const s16x8*)(parts + p * stride + base);
        #pragma unroll
        for (int j = 0; j < 8; ++j) s[j] += bf2f((u16)v[j]);
    }
    int cb = (int)(base % 2880);
    f32x4 b0 = *(const f32x4*)(bias + cb);
    f32x4 b1 = *(const f32x4*)(bias + cb + 4);
    f32x4 o0 = {s[0] + b0[0], s[1] + b0[1], s[2] + b0[2], s[3] + b0[3]};
    f32x4 o1 = {s[4] + b1[0], s[5] + b1[1], s[6] + b1[2], s[7] + b1[3]};
    *(f32x4*)(out + base)     = o0;
    *(f32x4*)(out + base + 4) = o1;
}

// ---------------------------------------------------------------------------
// Sliding-window GQA attention with sinks (unchanged, proven).
// ---------------------------------------------------------------------------
__global__ __launch_bounds__(256, 2) void attn_kernel(
    const u16* __restrict__ Q, const u16* __restrict__ Kb, const u16* __restrict__ Vb,
    const float* __restrict__ sinks, u16* __restrict__ Ob)
{
    __shared__ u16 Kls[64 * 64];
    __shared__ u16 Pls[4][16 * 72];

    const int h    = blockIdx.x;
    const int qblk = blockIdx.y;
    const int kvh  = h >> 3;
    const int tid  = threadIdx.x;
    const int lane = tid & 63;
    const int w    = tid >> 6;
    const int li   = lane & 15;
    const int lg   = lane >> 4;
    const int qw   = qblk * 64 + w * 16;

    s16x8 aq[2];
    {
        const u16* qrow = Q + ((size_t)(qw + li) * 64 + h) * 64 + lg * 8;
        aq[0] = *(const s16x8*)(qrow);
        aq[1] = *(const s16x8*)(qrow + 32);
    }

    const float snk = sinks[h];
    float m_run[4], l_run[4];
    f32x4 oacc[4];
    #pragma unroll
    for (int r = 0; r < 4; ++r) { m_run[r] = snk; l_run[r] = 1.0f; }
    #pragma unroll
    for (int ni = 0; ni < 4; ++ni) oacc[ni] = (f32x4){0.f, 0.f, 0.f, 0.f};

    const int srow = tid >> 3;
    const int slc  = (tid & 7) ^ (srow & 7);

    for (int t = 0; t < 3; ++t) {
        int jt = qblk - 2 + t;
        if (jt < 0) continue;
        int j0 = jt * 64;

        #pragma unroll
        for (int it = 0; it < 2; ++it) {
            const u16* src = Kb + ((size_t)(j0 + it * 32 + srow) * 8 + kvh) * 64 + slc * 8;
            GLOAD16(src, &Kls[(it * 256 + w * 64) * 8]);
        }
        __syncthreads();

        f32x4 sc[4];
        #pragma unroll
        for (int nf = 0; nf < 4; ++nf) {
            sc[nf] = (f32x4){0.f, 0.f, 0.f, 0.f};
            #pragma unroll
            for (int kc = 0; kc < 2; ++kc) {
                int row = nf * 16 + li;
                int ch  = (kc * 4 + lg) ^ (row & 7);
                s16x8 bk = *(const s16x8*)&Kls[row * 64 + ch * 8];
                sc[nf] = mfma_bf16(aq[kc], bk, sc[nf]);
            }
        }

        #pragma unroll
        for (int r = 0; r < 4; ++r) {
            const int qg = qw + lg * 4 + r;
            float mx = -1e30f;
            #pragma unroll
            for (int nf = 0; nf < 4; ++nf) {
                int jg = j0 + nf * 16 + li;
                bool ok = (jg <= qg) && (qg - jg < 128);
                float v = ok ? sc[nf][r] : -1e30f;
                sc[nf][r] = v;
                mx = fmaxf(mx, v);
            }
            #pragma unroll
            for (int off = 1; off < 16; off <<= 1)
                mx = fmaxf(mx, __shfl_xor(mx, off));
            float mnew = fmaxf(m_run[r], mx);
            float corr = __expf(m_run[r] - mnew);
            m_run[r] = mnew;
            float rs = 0.f;
            #pragma unroll
            for (int nf = 0; nf < 4; ++nf) {
                float p = __expf(sc[nf][r] - mnew);
                rs += p;
                Pls[w][(lg * 4 + r) * 72 + nf * 16 + li] = f2bf(p);
            }
            #pragma unroll
            for (int off = 1; off < 16; off <<= 1)
                rs += __shfl_xor(rs, off);
            l_run[r] = l_run[r] * corr + rs;
            #pragma unroll
            for (int ni = 0; ni < 4; ++ni) oacc[ni][r] *= corr;
        }
        __syncthreads();   // all K reads done; P writes drained

        #pragma unroll
        for (int kc = 0; kc < 2; ++kc) {
            s16x8 pa = *(const s16x8*)&Pls[w][li * 72 + kc * 32 + lg * 8];
            #pragma unroll
            for (int ni = 0; ni < 4; ++ni) {
                const u16* vsrc = Vb + ((size_t)(j0 + kc * 32 + lg * 8) * 8 + kvh) * 64 + ni * 16 + li;
                s16x8 bv;
                #pragma unroll
                for (int i = 0; i < 8; ++i) bv[i] = (short)vsrc[(size_t)i * 512];
                oacc[ni] = mfma_bf16(pa, bv, oacc[ni]);
            }
        }
    }

    #pragma unroll
    for (int r = 0; r < 4; ++r) {
        float inv = 1.0f / l_run[r];
        #pragma unroll
        for (int ni = 0; ni < 4; ++ni)
            Ob[((size_t)(qw + lg * 4 + r) * 64 + h) * 64 + ni * 16 + li] = f2bf(oacc[ni][r] * inv);
    }
}

// ---------------------------------------------------------------------------
extern "C" void kernel_launch(void* const* d_in, const int* in_sizes, int n_in,
                              void* d_out, int out_size, void* d_ws, size_t ws_size,
                              hipStream_t stream)
{
    const float* x     = (const float*)d_in[0];
    const float* wq_w  = (const float*)d_in[1];
    const float* wq_b  = (const float*)d_in[2];
    const float* wk_w  = (const float*)d_in[3];
    const float* wk_b  = (const float*)d_in[4];
    const float* wv_w  = (const float*)d_in[5];
    const float* wv_b  = (const float*)d_in[6];
    const float* wo_w  = (const float*)d_in[7];
    const float* wo_b  = (const float*)d_in[8];
    const float* sinks = (const float*)d_in[9];

    char* ws = (char*)d_ws;
    // Layout (peak 112.1 MB; 117.9 proven available):
    //   [0, 35,389,440)           xb|wqb|wkb|wvb        (cvt1 -> gemm1)
    //       after rope overlays:  qr@0|kr|vbf|attb      (rope -> gemm2)
    //   [35,389,440, 66,846,720)  qkvp 3 bf16 partials  (gemm1 -> rope)
    //   [58,982,400, 88,473,600)  oprt 5 bf16 partials  (gemm2 -> reduce)
    //       (overlaps dead qkvp tail -- qkvp dead after rope)
    //   [88,473,600, 112,066,560) wob                   (gemm1-launch cvt -> gemm2)
    u16*   xb   = (u16*)(ws + 0);
    u16*   wqb  = (u16*)(ws + 5898240ULL);
    u16*   wkb  = (u16*)(ws + 29491200ULL);
    u16*   wvb  = (u16*)(ws + 32440320ULL);
    u16*   qkvp = (u16*)(ws + 35389440ULL);      // 3 bf16 partials, stride 1024*5120
    u16*   qr   = (u16*)(ws + 0);
    u16*   kr   = (u16*)(ws + 8388608ULL);
    u16*   vbf  = (u16*)(ws + 9437184ULL);
    u16*   attb = (u16*)(ws + 10485760ULL);
    u16*   oprt = (u16*)(ws + 58982400ULL);      // 5 bf16 partials, stride 1024*2880
    u16*   wob  = (u16*)(ws + 88473600ULL);

    (void)in_sizes; (void)n_in; (void)out_size; (void)ws_size;

    // 1) bf16 conversions: x, wq, wk, wv only (wo rides inside gemm1 launch)
    cvt1_kernel<<<17280, 256, 0, stream>>>(x, wq_w, wk_w, wv_w, xb, wqb, wkb, wvb);
    // 2) fused QKV projection, split-K=3 -> 3 bf16 partials [1024][5120]
    //    grid.x = 320 GEMM blocks + 720 streaming-cvt blocks (wo -> wob, z==0;
    //    720 x 256 x 16 f32x4 = 2,949,120 = full wo). GEMM blocks ~4/CU.
    gemm_m97<<<dim3(1040, 1, 3), 256, 0, stream>>>(xb, 2880, 45, 40, 320,
        wqb, 32, 4096, 0,
        wkb, 4, 512, 4096,
        wvb, 4, 512, 4608,
        qkvp, 5120, 1024LL * 5120,
        wo_w, wob, 720);
    // 3) RoPE + partial-sum + bias + convert (q pre-scaled by 0.125)
    rope_kernel<<<1408, 256, 0, stream>>>(qkvp, wq_b, wk_b, wv_b, qr, kr, vbf);
    // 4) attention -> attb bf16 [1024][4096]
    attn_kernel<<<dim3(64, 16), 256, 0, stream>>>(qr, kr, vbf, sinks, attb);
    // 5) output projection, split-K=5 -> 5 bf16 partials [1024][2880]
    gemm_m97<<<dim3(192, 1, 5), 256, 0, stream>>>(attb, 4096, 64, 23, 192,
        wob, 23, 2880, 0,
        wob, 0, 0, 0,
        wob, 0, 0, 0,
        oprt, 2880, 1024LL * 2880,
        (const float*)nullptr, (u16*)nullptr, 0);
    // 6) reduce partials + bias -> d_out fp32 [1024][2880]
    reduce_out_kernel<<<1440, 256, 0, stream>>>(oprt, wo_b, (float*)d_out);
}